// Round 8
// baseline (112.737 us; speedup 1.0000x reference)
//
#include <hip/hip_runtime.h>
#include <math.h>

typedef float f32x4 __attribute__((ext_vector_type(4)));
typedef short bf16x8 __attribute__((ext_vector_type(8)));  // 8 bf16 in 4 VGPR

namespace {
constexpr int kB = 8, kL = 512, kD = 64, kS = 8;
constexpr int LP = 72;  // bf16 LDS row pad: 144B rows -> 2-way (free) on b128 frag reads
constexpr size_t SCL_OFF = 0;                                  // f32[4][8][8][512] = 512KB
constexpr size_t WT_OFF  = (size_t)4 * 8 * 8 * 512 * 4;        // 524288; wt bf16 64KB
}

__device__ __forceinline__ unsigned short f2bf(float f) {      // RNE float->bf16 bits
    unsigned u = __float_as_uint(f);
    u += 0x7FFFu + ((u >> 16) & 1u);
    return (unsigned short)(u >> 16);
}
__device__ __forceinline__ unsigned pk2(float lo, float hi) {
    return (unsigned)f2bf(lo) | ((unsigned)f2bf(hi) << 16);
}

// ---------------- P: W^T -> bf16 (blocks 0..7) + scalar dots scl (blocks 8..71) ----------
__global__ __launch_bounds__(256) void grn_prep(
    const float* __restrict__ lstm1, const float* __restrict__ lstm2,
    const float* __restrict__ W, const float* __restrict__ V,
    const float* __restrict__ Wg, unsigned char* __restrict__ ws)
{
    float* scl = (float*)(ws + SCL_OFF);
    unsigned short* wt = (unsigned short*)(ws + WT_OFF);
    const int tid = threadIdx.x;
    if (blockIdx.x < 8) {
        const int s = blockIdx.x;
        __shared__ float wsm[64][68];
        const float* pw = W + s * 4096;
        const int row = tid >> 2, c0 = (tid & 3) * 16;
        #pragma unroll
        for (int q = 0; q < 4; q++)
            *(float4*)&wsm[row][c0 + q * 4] = *(const float4*)(pw + row * 64 + c0 + q * 4);
        __syncthreads();
        // wt[s][e][d] = W[s][d][e]
        const int e = tid >> 2, d0 = (tid & 3) * 16;
        unsigned wd[8];
        #pragma unroll
        for (int q = 0; q < 8; q++)
            wd[q] = pk2(wsm[d0 + 2 * q][e], wsm[d0 + 2 * q + 1][e]);
        unsigned short* dst = wt + s * 4096 + e * 64 + d0;
        uint4 a = {wd[0], wd[1], wd[2], wd[3]};
        uint4 c = {wd[4], wd[5], wd[6], wd[7]};
        *(uint4*)(dst) = a;
        *(uint4*)(dst + 8) = c;
    } else {
        const int rb = blockIdx.x - 8;
        const int b = rb >> 3, r0 = (rb & 7) * 64;
        const int kind = tid & 3, row = r0 + (tid >> 2);
        const float* x = (kind < 2 ? lstm1 : lstm2) + ((size_t)b * kL + row) * kD;
        float xr[64];
        #pragma unroll
        for (int q = 0; q < 16; q++)
            *(float4*)&xr[q * 4] = *(const float4*)(x + q * 4);
        const float* vb = (kind & 1 ? Wg : V) + ((kind >> 1) ? kD : 0);
        #pragma unroll
        for (int s = 0; s < kS; s++) {
            const float* vec = vb + s * 2 * kD;
            float a = 0.f;
            #pragma unroll
            for (int q = 0; q < 16; q++) {
                const float4 vv = *(const float4*)(vec + q * 4);
                a = fmaf(vv.x, xr[q * 4 + 0], a);
                a = fmaf(vv.y, xr[q * 4 + 1], a);
                a = fmaf(vv.z, xr[q * 4 + 2], a);
                a = fmaf(vv.w, xr[q * 4 + 3], a);
            }
            scl[(((size_t)kind * 8 + b) * 8 + s) * 512 + row] = a;
        }
    }
}

// WB loader: full-e W_s fragments for one wave (8 x uint4, coalesced, L1-hot)
__device__ __forceinline__ void load_wb(
    bf16x8 WB[4][2], const unsigned short* __restrict__ wt, int s, int fr, int fh)
{
    #pragma unroll
    for (int ne = 0; ne < 4; ne++)
        #pragma unroll
        for (int kb = 0; kb < 2; kb++)
            WB[ne][kb] = *(const bf16x8*)(wt + s * 4096 + (ne * 16 + fr) * 64
                                          + fh * 8 + kb * 32);
}

// One s-iteration for one wave: T_s(32x64) -> private LDS -> rw(32x32) -> epilogue
__device__ __forceinline__ void grn_body(
    const bf16x8 WB[4][2], const bf16x8 A1[2][2], const bf16x8 Bf[2][2],
    unsigned short (*__restrict__ tsw)[LP], const float scl[4][kS][64],
    float oacc[2][2][4], int s, int fr, int fh, int wm, int wn,
    float us, float bgs)
{
    // T = x1 @ W_s^T : 2 mb x 4 ne tiles, K=64
    #pragma unroll
    for (int mb = 0; mb < 2; mb++)
        #pragma unroll
        for (int ne = 0; ne < 4; ne++) {
            f32x4 z = {0.f, 0.f, 0.f, 0.f};
            f32x4 t = __builtin_amdgcn_mfma_f32_16x16x32_bf16(A1[mb][0], WB[ne][0], z, 0, 0, 0);
            t = __builtin_amdgcn_mfma_f32_16x16x32_bf16(A1[mb][1], WB[ne][1], t, 0, 0, 0);
            #pragma unroll
            for (int r = 0; r < 4; r++)    // D: col=fr (e), row=fh*4+r (i)
                tsw[mb * 16 + fh * 4 + r][ne * 16 + fr] = f2bf(t[r]);
        }
    // rw = T @ x2^T  (A from private ts; compiler inserts lgkmcnt for the RAW)
    bf16x8 At[2][2];
    #pragma unroll
    for (int mb = 0; mb < 2; mb++)
        #pragma unroll
        for (int kb = 0; kb < 2; kb++)
            At[mb][kb] = *(const bf16x8*)&tsw[mb * 16 + fr][fh * 8 + kb * 32];
    #pragma unroll
    for (int mb = 0; mb < 2; mb++)
        #pragma unroll
        for (int nb = 0; nb < 2; nb++) {
            f32x4 z = {0.f, 0.f, 0.f, 0.f};
            f32x4 acc = __builtin_amdgcn_mfma_f32_16x16x32_bf16(At[mb][0], Bf[nb][0], z, 0, 0, 0);
            acc = __builtin_amdgcn_mfma_f32_16x16x32_bf16(At[mb][1], Bf[nb][1], acc, 0, 0, 0);
            const int jj = wn * 32 + nb * 16 + fr;
            const float v2 = scl[2][s][jj], g2 = scl[3][s][jj];
            #pragma unroll
            for (int r = 0; r < 4; r++) {
                const int ii = wm * 32 + mb * 16 + fh * 4 + r;
                const float v1 = scl[0][s][ii], g1 = scl[1][s][ii];
                const float gate = 1.f / (1.f + __expf(-(g1 + g2 + bgs)));
                const float sv = 1.f / (1.f + __expf(-(v1 + v2)));
                const float res = fmaf(gate, acc[r] - sv, sv);  // gate*rw+(1-gate)*sv
                oacc[mb][nb][r] = fmaf(us, res, oacc[mb][nb][r]);
            }
        }
}

// ---------------- Fused main: barrier-free after staging; wave-private T scratch --------
__global__ __launch_bounds__(256, 2) void grn_fusedm(
    const float* __restrict__ lstm1, const float* __restrict__ lstm2,
    const float* __restrict__ bS, const float* __restrict__ bg,
    const float* __restrict__ u, const unsigned char* __restrict__ ws,
    float* __restrict__ out)
{
    const float* sclw = (const float*)(ws + SCL_OFF);
    const unsigned short* wt = (const unsigned short*)(ws + WT_OFF);
    const int jt = blockIdx.x, it = blockIdx.y, b = blockIdx.z;
    __shared__ __align__(16) unsigned short x1t[64][LP];
    __shared__ __align__(16) unsigned short x2t[64][LP];
    __shared__ __align__(16) unsigned short ts[4][32][LP];   // wave-private T scratch
    __shared__ float scl[4][kS][64];
    const int tid = threadIdx.x;
    {   // x1/x2 tiles f32 -> bf16 LDS
        const float* p1 = lstm1 + ((size_t)b * kL + it * 64) * kD;
        const float* p2 = lstm2 + ((size_t)b * kL + jt * 64) * kD;
        const int row = tid >> 2, c0 = (tid & 3) * 16;
        unsigned w1[8], w2[8];
        #pragma unroll
        for (int q = 0; q < 4; q++) {
            const float4 a = *(const float4*)(p1 + row * 64 + c0 + q * 4);
            const float4 c = *(const float4*)(p2 + row * 64 + c0 + q * 4);
            w1[q * 2] = pk2(a.x, a.y); w1[q * 2 + 1] = pk2(a.z, a.w);
            w2[q * 2] = pk2(c.x, c.y); w2[q * 2 + 1] = pk2(c.z, c.w);
        }
        uint4 a0 = {w1[0], w1[1], w1[2], w1[3]}, a1 = {w1[4], w1[5], w1[6], w1[7]};
        uint4 c0v = {w2[0], w2[1], w2[2], w2[3]}, c1 = {w2[4], w2[5], w2[6], w2[7]};
        *(uint4*)&x1t[row][c0] = a0; *(uint4*)&x1t[row][c0 + 8] = a1;
        *(uint4*)&x2t[row][c0] = c0v; *(uint4*)&x2t[row][c0 + 8] = c1;
    }
    {   // scl slices: kinds 0,1 use it-rows; 2,3 use jt-rows
        const int p0 = tid * 8, kind = p0 >> 9, rem = p0 & 511, s = rem >> 6, cc = rem & 63;
        const int base = (kind < 2 ? it : jt) * 64;
        const float* g = sclw + (((size_t)kind * 8 + b) * 8 + s) * 512 + base + cc;
        *(float4*)&scl[kind][s][cc] = *(const float4*)g;
        *(float4*)&scl[kind][s][cc + 4] = *(const float4*)(g + 4);
    }
    __syncthreads();   // the ONLY barrier
    const int lane = tid & 63, w = tid >> 6;
    const int wm = w >> 1, wn = w & 1;
    const int fr = lane & 15, fh = lane >> 4;
    unsigned short (*__restrict__ tsw)[LP] = ts[w];
    bf16x8 A1[2][2], Bf[2][2];
    #pragma unroll
    for (int mb = 0; mb < 2; mb++)
        #pragma unroll
        for (int kb = 0; kb < 2; kb++)
            A1[mb][kb] = *(const bf16x8*)&x1t[wm * 32 + mb * 16 + fr][fh * 8 + kb * 32];
    #pragma unroll
    for (int nb = 0; nb < 2; nb++)
        #pragma unroll
        for (int kb = 0; kb < 2; kb++)
            Bf[nb][kb] = *(const bf16x8*)&x2t[wn * 32 + nb * 16 + fr][fh * 8 + kb * 32];
    float ur[kS], bgr[kS];
    #pragma unroll
    for (int s = 0; s < kS; s++) { ur[s] = u[s]; bgr[s] = bS[s]; }  // reuse bgr temp for bias
    float bias_c = 0.f;
    #pragma unroll
    for (int s = 0; s < kS; s++) bias_c = fmaf(ur[s], bgr[s], bias_c);
    #pragma unroll
    for (int s = 0; s < kS; s++) bgr[s] = bg[s];
    float oacc[2][2][4];
    #pragma unroll
    for (int mb = 0; mb < 2; mb++)
        #pragma unroll
        for (int nb = 0; nb < 2; nb++)
            #pragma unroll
            for (int r = 0; r < 4; r++) oacc[mb][nb][r] = bias_c;

    // software-pipelined W double-buffer (named sets, static indexing)
    bf16x8 WBa[4][2], WBb[4][2];
    load_wb(WBa, wt, 0, fr, fh);
    #pragma unroll 1
    for (int s = 0; s < kS; s += 2) {
        load_wb(WBb, wt, s + 1, fr, fh);
        grn_body(WBa, A1, Bf, tsw, scl, oacc, s, fr, fh, wm, wn, ur[s], bgr[s]);
        load_wb(WBa, wt, (s + 2) & 7, fr, fh);
        grn_body(WBb, A1, Bf, tsw, scl, oacc, s + 1, fr, fh, wm, wn, ur[s + 1], bgr[s + 1]);
    }
    float* op = out + ((size_t)b * kL + it * 64) * kL + jt * 64;
    #pragma unroll
    for (int mb = 0; mb < 2; mb++)
        #pragma unroll
        for (int nb = 0; nb < 2; nb++)
            #pragma unroll
            for (int r = 0; r < 4; r++)
                op[(wm * 32 + mb * 16 + fh * 4 + r) * kL + wn * 32 + nb * 16 + fr]
                    = oacc[mb][nb][r];
}

extern "C" void kernel_launch(void* const* d_in, const int* in_sizes, int n_in,
                              void* d_out, int out_size, void* d_ws, size_t ws_size,
                              hipStream_t stream) {
    const float* lstm1 = (const float*)d_in[0];
    const float* lstm2 = (const float*)d_in[1];
    const float* W     = (const float*)d_in[2];
    const float* V     = (const float*)d_in[3];
    const float* bS    = (const float*)d_in[4];
    const float* Wg    = (const float*)d_in[5];
    const float* bg    = (const float*)d_in[6];
    const float* u     = (const float*)d_in[7];
    unsigned char* ws = (unsigned char*)d_ws;   // uses ~576 KB; ws_size = 256 MiB
    grn_prep<<<72, 256, 0, stream>>>(lstm1, lstm2, W, V, Wg, ws);
    grn_fusedm<<<dim3(kL / 64, kL / 64, kB), 256, 0, stream>>>(
        lstm1, lstm2, bS, bg, u, ws, (float*)d_out);
}